// Round 22
// baseline (283.294 us; speedup 1.0000x reference)
//
#include <hip/hip_runtime.h>
#include <hip/hip_bf16.h>

#define T_TOK 2048
#define DIM   1024
#define NEXP  16
#define HID   2048
#define MAXMT 32

typedef __attribute__((ext_vector_type(8))) short short8;
typedef __attribute__((ext_vector_type(4))) float f32x4;

__device__ __forceinline__ unsigned short f2bf(float f) {
  __hip_bfloat16 h = __float2bfloat16(f);
  union { __hip_bfloat16 b; unsigned short u; } cv; cv.b = h; return cv.u;
}
__device__ __forceinline__ float bf2f(unsigned short u) {
  union { unsigned int i; float f; } cv; cv.i = ((unsigned int)u) << 16; return cv.f;
}

// async global->LDS, 16 B per lane; dst must be wave-uniform base (+lane*16)
__device__ __forceinline__ void glds16(const void* g, void* l) {
  __builtin_amdgcn_global_load_lds(
      (const __attribute__((address_space(1))) unsigned int*)g,
      (__attribute__((address_space(3))) unsigned int*)l, 16, 0, 0);
}

// ---------------- router: Wr staged in LDS; also emits bf16 xg -------------
__global__ __launch_bounds__(256) void router_k(const float* __restrict__ x,
    const float* __restrict__ Wr, const float* __restrict__ br,
    int* __restrict__ re, float* __restrict__ rwv, int* __restrict__ cnt,
    unsigned short* __restrict__ xg)
{
  __shared__ float wl[NEXP][DIM + 1];
  const int tid = threadIdx.x;
#pragma unroll
  for (int i = 0; i < 16; i++) {
    const int flat = tid + 256 * i;
    const int d = flat >> 2, e4 = (flat & 3) * 4;
    float4 v = *reinterpret_cast<const float4*>(Wr + (size_t)d * NEXP + e4);
    wl[e4 + 0][d] = v.x; wl[e4 + 1][d] = v.y;
    wl[e4 + 2][d] = v.z; wl[e4 + 3][d] = v.w;
  }
  __syncthreads();
  const int wid = tid >> 6, lane = tid & 63;
  for (int tt = 0; tt < 8; tt++) {
    const int t = blockIdx.x * 32 + wid * 8 + tt;
    const float* xr = x + (size_t)t * DIM;
    unsigned short* xo = xg + (size_t)t * DIM;
    float acc[NEXP];
#pragma unroll
    for (int e = 0; e < NEXP; e++) acc[e] = 0.f;
    for (int i = 0; i < DIM / 64; i++) {
      const int d = lane + 64 * i;
      const float xv = xr[d];
      xo[d] = f2bf(xv);                        // fused bf16 convert
#pragma unroll
      for (int e = 0; e < NEXP; e++) acc[e] += xv * wl[e][d];
    }
#pragma unroll
    for (int e = 0; e < NEXP; e++) {
      float v = acc[e];
      v += __shfl_xor(v, 32); v += __shfl_xor(v, 16); v += __shfl_xor(v, 8);
      v += __shfl_xor(v, 4);  v += __shfl_xor(v, 2);  v += __shfl_xor(v, 1);
      acc[e] = v;
    }
    if (lane == 0) {
      float lg[NEXP];
#pragma unroll
      for (int e = 0; e < NEXP; e++) lg[e] = acc[e] + br[e];  // TEMP = 1.0
      int e0 = 0; float b0 = lg[0];
      for (int e = 1; e < NEXP; e++) if (lg[e] > b0) { b0 = lg[e]; e0 = e; }
      int e1 = (e0 == 0) ? 1 : 0; float b1v = lg[e1];
      for (int e = 0; e < NEXP; e++) if (e != e0 && lg[e] > b1v) { b1v = lg[e]; e1 = e; }
      float p1 = expf(b1v - b0);               // p0 = 1
      float inv = 1.0f / (1.0f + p1);
      re[2*t] = e0; re[2*t+1] = e1;
      rwv[2*t] = inv; rwv[2*t+1] = p1 * inv;
      atomicAdd(&cnt[e0], 1); atomicAdd(&cnt[e1], 1);
    }
  }
}

// ---------------- scan: prefix + flat m-tile list (BM=256) ----------------
__global__ void scan_k(const int* cnt, int* basev, int* tile_e, int* tile_m0, int* ntt) {
  if (threadIdx.x == 0) {
    int s = 0, t = 0;
    for (int e = 0; e < NEXP; e++) {
      basev[e] = s;
      for (int m0 = 0; m0 < cnt[e]; m0 += 256) { tile_e[t] = e; tile_m0[t] = m0; t++; }
      s += cnt[e];
    }
    ntt[0] = t;
  }
}

// ---------------- scatter: build per-expert row lists ----------------
__global__ __launch_bounds__(256) void scatter_k(const int* __restrict__ re,
    const float* __restrict__ rwv, const int* __restrict__ basev, int* fill,
    int* __restrict__ rows_token, float* __restrict__ rows_w, int* __restrict__ slot_of)
{
  int t = blockIdx.x * 256 + threadIdx.x;
  if (t >= T_TOK) return;
  for (int k = 0; k < 2; k++) {
    int e = re[2*t+k];
    int pos = atomicAdd(&fill[e], 1);
    int row = basev[e] + pos;
    rows_token[row] = t;
    rows_w[row] = rwv[2*t+k];
    slot_of[2*t+k] = row;
  }
}

// ---------------- grouped expert GEMM: BM=256 x BN=128, 256 thr, split-K ---
// CU-byte reduction round: BN=128 halves the A-re-read term (the dominant
// CU-side VMEM traffic); BM=256 keeps W read ~once.  256 thr = 4 waves, each
// wave owns 64x128 (acc[4][8], 64 MFMA/phase) -- staging patterns identical
// to the proven R17 core (A glds16+T2; B fp32 reg-staged transpose, depth-1).
// fc1 splitK=2 -> bf16 partials (GELU in gelu_k); fc2 splitK=4 -> bf16
// partials (weighted), summed in combine.  Grids: 544 blocks each.
template<bool FC1>
__global__ __launch_bounds__(256, 2) void expert_gemm_k(
    const unsigned short* __restrict__ Ag,     // bf16: FC1 xg[tok][KD], else hbuf[row][KD]
    const float* __restrict__ Wg,              // fp32 [e][KD][ND]
    const float* __restrict__ bg,
    const int* __restrict__ cnt, const int* __restrict__ basev,
    const int* __restrict__ tile_e, const int* __restrict__ tile_m0,
    const int* __restrict__ ntt, const float* __restrict__ rows_w,
    const int* __restrict__ rows_token,
    unsigned short* __restrict__ pout)          // bf16 partials [kz][4096][ND]
{
  constexpr int KD = FC1 ? DIM : HID;
  constexpr int ND = FC1 ? HID : DIM;
  constexpr int KSPL = FC1 ? 2 : 4;
  constexpr int KLOC = KD / KSPL;               // 512 both
  constexpr int BM = 256, BN = 128, BK = 64, LDPB = 68;
  constexpr int NPH = KLOC / BK;                // 8 phases
  if ((int)blockIdx.y >= ntt[0]) return;
  const int e  = tile_e[blockIdx.y], m0 = tile_m0[blockIdx.y];
  const int Ne = cnt[e], base = basev[e];
  const int nt = blockIdx.x, kz = blockIdx.z;
  const int kbase = kz * KLOC;
  __shared__ unsigned short As[BM][BK];        // 32 KB, linear (glds dest)
  __shared__ unsigned short Bs[BN][LDPB];      // 17 KB, transposed [n][k]
  const int tid = threadIdx.x, lane = tid & 63, wid = tid >> 6;

  // A staging: lane -> row lrow = lane>>3, src chunk = (lane&7)^(lrow&7) (T2)
  const int lrow = lane >> 3;
  const int lchunk = ((lane & 7) ^ (lrow & 7)) * 8;
  const unsigned short* asrc[8];
  unsigned short* aldst[8];
#pragma unroll
  for (int j = 0; j < 8; j++) {
    const int r = j * 32 + wid * 8 + lrow;
    int g = m0 + r; if (g >= Ne) g = Ne - 1;
    if constexpr (FC1) {
      const int tok = rows_token[base + g];    // indirect gather from xg
      asrc[j] = Ag + (size_t)tok * KD + kbase + lchunk;
    } else {
      asrc[j] = Ag + (size_t)(base + g) * KD + kbase + lchunk;
    }
    aldst[j] = &As[j * 32 + wid * 8][0];       // wave-uniform base
  }
  // B staging: thread t covers n4 = (t&31)*4, k-rows kr = (t>>5) + 8j, j=0..7
  const int bn4 = (tid & 31) * 4, bkr = tid >> 5;
  const float* bsrc = Wg + (size_t)e * KD * ND + (size_t)(kbase + bkr) * ND
                      + nt * BN + bn4;

  const int lr = lane & 15, lg = lane >> 4;
  const bool wactive = (m0 + wid * 64) < Ne;   // 4 waves stacked in m

  // A fragment pointers with matching XOR: chunk = (lg+4h) ^ (lr&7)
  const unsigned short* afp[4][2];
#pragma unroll
  for (int m = 0; m < 4; m++)
#pragma unroll
    for (int h = 0; h < 2; h++)
      afp[m][h] = &As[wid * 64 + m * 16 + lr][(((lg + 4*h) ^ (lr & 7)) * 8)];

  f32x4 acc[4][8];
#pragma unroll
  for (int m = 0; m < 4; m++)
#pragma unroll
    for (int n = 0; n < 8; n++) acc[m][n] = (f32x4){0.f, 0.f, 0.f, 0.f};

  float4 bst[8];
#define LOADB(K0)                                                            \
  { _Pragma("unroll")                                                        \
    for (int j = 0; j < 8; j++)                                              \
      bst[j] = *reinterpret_cast<const float4*>(bsrc + (size_t)((K0) + 8 * j) * ND); }

  // prologue: B fp32 for phase 0
  LOADB(0)

  for (int ph = 0; ph < NPH; ++ph) {
    const int k0 = ph * BK;
    __syncthreads();                           // prior phase's readers done
#pragma unroll
    for (int j = 0; j < 8; j++) glds16(asrc[j] + k0, aldst[j]);
    // write staged B (transpose into Bs[n][k])
#pragma unroll
    for (int j = 0; j < 8; j++) {
      Bs[bn4 + 0][bkr + 8 * j] = f2bf(bst[j].x);
      Bs[bn4 + 1][bkr + 8 * j] = f2bf(bst[j].y);
      Bs[bn4 + 2][bkr + 8 * j] = f2bf(bst[j].z);
      Bs[bn4 + 3][bkr + 8 * j] = f2bf(bst[j].w);
    }
    __syncthreads();                           // drain (glds + ds_write)
    if (ph + 1 < NPH) LOADB((ph + 1) * BK)     // prefetch next B under MFMA
    if (wactive) {
      __builtin_amdgcn_s_setprio(1);
#pragma unroll
      for (int h = 0; h < 2; h++) {
        short8 af[4];
#pragma unroll
        for (int m = 0; m < 4; m++)
          af[m] = *reinterpret_cast<const short8*>(afp[m][h]);
#pragma unroll
        for (int n = 0; n < 8; n++) {
          const short8 bb = *reinterpret_cast<const short8*>(
              &Bs[n * 16 + lr][(lg + 4*h) * 8]);
#pragma unroll
          for (int m = 0; m < 4; m++)
            acc[m][n] = __builtin_amdgcn_mfma_f32_16x16x32_bf16(af[m], bb,
                                                                acc[m][n], 0, 0, 0);
        }
      }
      __builtin_amdgcn_s_setprio(0);
    }
  }
#undef LOADB

  if (!wactive) return;
  // epilogue: bf16 partial writes (C/D layout col=lane&15, row=(lane>>4)*4+v)
  constexpr size_t PSZ = (size_t)(2 * T_TOK) * ND;
#pragma unroll
  for (int n = 0; n < 8; n++) {
    const int col = nt * BN + n * 16 + lr;
    const float bias = (kz == 0) ? bg[(size_t)e * ND + col] : 0.f;
#pragma unroll
    for (int m = 0; m < 4; m++) {
      const int rbase = m0 + wid * 64 + m * 16 + lg * 4;
#pragma unroll
      for (int v = 0; v < 4; v++) {
        const int r = rbase + v;
        if (r < Ne) {
          float val = acc[m][n][v] + bias;
          if constexpr (!FC1) val *= rows_w[base + r];
          pout[(size_t)kz * PSZ + (size_t)(base + r) * ND + col] = f2bf(val);
        }
      }
    }
  }
}

// ---------------- gelu: hbuf = bf16(GELU(hp0 + hp1)) ----------------
__global__ __launch_bounds__(256) void gelu_k(const unsigned short* __restrict__ hpart,
                                              unsigned short* __restrict__ hbuf)
{
  const size_t PSZ = (size_t)(2 * T_TOK) * HID;
  const size_t off = (size_t)blockIdx.x * HID + threadIdx.x * 8;
  ushort4 a0 = *reinterpret_cast<const ushort4*>(hpart + off);
  ushort4 a1 = *reinterpret_cast<const ushort4*>(hpart + off + 4);
  ushort4 b0 = *reinterpret_cast<const ushort4*>(hpart + PSZ + off);
  ushort4 b1 = *reinterpret_cast<const ushort4*>(hpart + PSZ + off + 4);
  unsigned short o[8];
  float v;
#define G(UA, UB, I)                                                         \
  v = bf2f(UA) + bf2f(UB);                                                   \
  v = 0.5f * v * (1.0f + erff(v * 0.70710678118654752440f));                 \
  o[I] = f2bf(v);
  G(a0.x, b0.x, 0) G(a0.y, b0.y, 1) G(a0.z, b0.z, 2) G(a0.w, b0.w, 3)
  G(a1.x, b1.x, 4) G(a1.y, b1.y, 5) G(a1.z, b1.z, 6) G(a1.w, b1.w, 7)
#undef G
  *reinterpret_cast<ushort4*>(hbuf + off)     = *reinterpret_cast<ushort4*>(&o[0]);
  *reinterpret_cast<ushort4*>(hbuf + off + 4) = *reinterpret_cast<ushort4*>(&o[4]);
}

// ---------------- combine: y = x + sum of 4 partials over 2 slots ----------
__global__ __launch_bounds__(256) void combine_k(const float* __restrict__ x,
    const unsigned short* __restrict__ opart, const int* __restrict__ slot_of,
    float* __restrict__ out)
{
  const int t = blockIdx.x, c = threadIdx.x;   // 256 thr x 4 floats
  const int s0 = slot_of[2*t], s1 = slot_of[2*t+1];
  const size_t PSZ = (size_t)(2 * T_TOK) * DIM;
  const float4 a = reinterpret_cast<const float4*>(x + (size_t)t * DIM)[c];
  float r0 = a.x, r1 = a.y, r2 = a.z, r3 = a.w;
#pragma unroll
  for (int kz = 0; kz < 4; kz++) {
    ushort4 p = *reinterpret_cast<const ushort4*>(
        opart + kz * PSZ + (size_t)s0 * DIM + c * 4);
    r0 += bf2f(p.x); r1 += bf2f(p.y); r2 += bf2f(p.z); r3 += bf2f(p.w);
    ushort4 q = *reinterpret_cast<const ushort4*>(
        opart + kz * PSZ + (size_t)s1 * DIM + c * 4);
    r0 += bf2f(q.x); r1 += bf2f(q.y); r2 += bf2f(q.z); r3 += bf2f(q.w);
  }
  float4 r; r.x = r0; r.y = r1; r.z = r2; r.w = r3;
  reinterpret_cast<float4*>(out + (size_t)t * DIM)[c] = r;
}

extern "C" void kernel_launch(void* const* d_in, const int* in_sizes, int n_in,
                              void* d_out, int out_size, void* d_ws, size_t ws_size,
                              hipStream_t stream) {
  const float* x  = (const float*)d_in[0];
  const float* Wr = (const float*)d_in[1];
  const float* br = (const float*)d_in[2];
  const float* W1 = (const float*)d_in[3];
  const float* b1 = (const float*)d_in[4];
  const float* W2 = (const float*)d_in[5];
  const float* b2 = (const float*)d_in[6];
  float* out = (float*)d_out;
  char* ws = (char*)d_ws;

  int*   cnt        = (int*)  (ws + 0);
  int*   fill       = (int*)  (ws + 64);
  int*   basev      = (int*)  (ws + 128);
  int*   ntt        = (int*)  (ws + 192);
  int*   tile_e     = (int*)  (ws + 1024);
  int*   tile_m0    = (int*)  (ws + 2048);
  int*   re         = (int*)  (ws + 16384);
  float* rwv        = (float*)(ws + 32768);
  int*   rows_token = (int*)  (ws + 49152);
  float* rows_w     = (float*)(ws + 65536);
  int*   slot_of    = (int*)  (ws + 81920);
  unsigned short* xg    = (unsigned short*)(ws + ((size_t)(1 << 17)));                       // 4 MB
  unsigned short* hbuf  = (unsigned short*)(ws + ((size_t)(1 << 17) + ((size_t)8   << 20))); // 16 MB
  unsigned short* hpart = (unsigned short*)(ws + ((size_t)(1 << 17) + ((size_t)24  << 20))); // 2x16 MB
  unsigned short* opart = (unsigned short*)(ws + ((size_t)(1 << 17) + ((size_t)56  << 20))); // 4x8 MB

  hipMemsetAsync(ws, 0, 256, stream);          // cnt / fill / basev / ntt
  router_k<<<dim3(T_TOK / 32), dim3(256), 0, stream>>>(x, Wr, br, re, rwv, cnt, xg);
  scan_k<<<dim3(1), dim3(64), 0, stream>>>(cnt, basev, tile_e, tile_m0, ntt);
  scatter_k<<<dim3(T_TOK / 256), dim3(256), 0, stream>>>(re, rwv, basev, fill,
                                                         rows_token, rows_w, slot_of);
  expert_gemm_k<true><<<dim3(HID / 128, MAXMT, 2), dim3(256), 0, stream>>>(
      xg, W1, b1, cnt, basev, tile_e, tile_m0, ntt, rows_w, rows_token, hpart);
  gelu_k<<<dim3(2 * T_TOK), dim3(256), 0, stream>>>(hpart, hbuf);
  expert_gemm_k<false><<<dim3(DIM / 128, MAXMT, 4), dim3(256), 0, stream>>>(
      hbuf, W2, b2, cnt, basev, tile_e, tile_m0, ntt, rows_w, rows_token, opart);
  combine_k<<<dim3(T_TOK), dim3(256), 0, stream>>>(x, opart, slot_of, out);
}

// Round 23
// 214.715 us; speedup vs baseline: 1.3194x; 1.3194x over previous
//
#include <hip/hip_runtime.h>
#include <hip/hip_bf16.h>

#define T_TOK 2048
#define DIM   1024
#define NEXP  16
#define HID   2048
#define MAXMT 32

typedef __attribute__((ext_vector_type(8))) short short8;
typedef __attribute__((ext_vector_type(4))) float f32x4;

__device__ __forceinline__ unsigned short f2bf(float f) {
  __hip_bfloat16 h = __float2bfloat16(f);
  union { __hip_bfloat16 b; unsigned short u; } cv; cv.b = h; return cv.u;
}
__device__ __forceinline__ float bf2f(unsigned short u) {
  union { unsigned int i; float f; } cv; cv.i = ((unsigned int)u) << 16; return cv.f;
}

// async global->LDS, 16 B per lane; dst must be wave-uniform base (+lane*16)
__device__ __forceinline__ void glds16(const void* g, void* l) {
  __builtin_amdgcn_global_load_lds(
      (const __attribute__((address_space(1))) unsigned int*)g,
      (__attribute__((address_space(3))) unsigned int*)l, 16, 0, 0);
}

// ---------------- router: Wr staged in LDS; also emits bf16 xg -------------
// Fused conv: each token row is already read here; write xg[t][d] = bf16(x).
__global__ __launch_bounds__(256) void router_k(const float* __restrict__ x,
    const float* __restrict__ Wr, const float* __restrict__ br,
    int* __restrict__ re, float* __restrict__ rwv, int* __restrict__ cnt,
    unsigned short* __restrict__ xg)
{
  __shared__ float wl[NEXP][DIM + 1];
  const int tid = threadIdx.x;
#pragma unroll
  for (int i = 0; i < 16; i++) {
    const int flat = tid + 256 * i;
    const int d = flat >> 2, e4 = (flat & 3) * 4;
    float4 v = *reinterpret_cast<const float4*>(Wr + (size_t)d * NEXP + e4);
    wl[e4 + 0][d] = v.x; wl[e4 + 1][d] = v.y;
    wl[e4 + 2][d] = v.z; wl[e4 + 3][d] = v.w;
  }
  __syncthreads();
  const int wid = tid >> 6, lane = tid & 63;
  for (int tt = 0; tt < 8; tt++) {
    const int t = blockIdx.x * 32 + wid * 8 + tt;
    const float* xr = x + (size_t)t * DIM;
    unsigned short* xo = xg + (size_t)t * DIM;
    float acc[NEXP];
#pragma unroll
    for (int e = 0; e < NEXP; e++) acc[e] = 0.f;
    for (int i = 0; i < DIM / 64; i++) {
      const int d = lane + 64 * i;
      const float xv = xr[d];
      xo[d] = f2bf(xv);                        // fused bf16 convert
#pragma unroll
      for (int e = 0; e < NEXP; e++) acc[e] += xv * wl[e][d];
    }
#pragma unroll
    for (int e = 0; e < NEXP; e++) {
      float v = acc[e];
      v += __shfl_xor(v, 32); v += __shfl_xor(v, 16); v += __shfl_xor(v, 8);
      v += __shfl_xor(v, 4);  v += __shfl_xor(v, 2);  v += __shfl_xor(v, 1);
      acc[e] = v;
    }
    if (lane == 0) {
      float lg[NEXP];
#pragma unroll
      for (int e = 0; e < NEXP; e++) lg[e] = acc[e] + br[e];  // TEMP = 1.0
      int e0 = 0; float b0 = lg[0];
      for (int e = 1; e < NEXP; e++) if (lg[e] > b0) { b0 = lg[e]; e0 = e; }
      int e1 = (e0 == 0) ? 1 : 0; float b1v = lg[e1];
      for (int e = 0; e < NEXP; e++) if (e != e0 && lg[e] > b1v) { b1v = lg[e]; e1 = e; }
      float p1 = expf(b1v - b0);               // p0 = 1
      float inv = 1.0f / (1.0f + p1);
      re[2*t] = e0; re[2*t+1] = e1;
      rwv[2*t] = inv; rwv[2*t+1] = p1 * inv;
      atomicAdd(&cnt[e0], 1); atomicAdd(&cnt[e1], 1);
    }
  }
}

// ---------------- scan: prefix + flat m-tile list (BM=256) ----------------
__global__ void scan_k(const int* cnt, int* basev, int* tile_e, int* tile_m0, int* ntt) {
  if (threadIdx.x == 0) {
    int s = 0, t = 0;
    for (int e = 0; e < NEXP; e++) {
      basev[e] = s;
      for (int m0 = 0; m0 < cnt[e]; m0 += 256) { tile_e[t] = e; tile_m0[t] = m0; t++; }
      s += cnt[e];
    }
    ntt[0] = t;
  }
}

// ---------------- scatter: build per-expert row lists ----------------
__global__ __launch_bounds__(256) void scatter_k(const int* __restrict__ re,
    const float* __restrict__ rwv, const int* __restrict__ basev, int* fill,
    int* __restrict__ rows_token, float* __restrict__ rows_w, int* __restrict__ slot_of)
{
  int t = blockIdx.x * 256 + threadIdx.x;
  if (t >= T_TOK) return;
  for (int k = 0; k < 2; k++) {
    int e = re[2*t+k];
    int pos = atomicAdd(&fill[e], 1);
    int row = basev[e] + pos;
    rows_token[row] = t;
    rows_w[row] = rwv[2*t+k];
    slot_of[2*t+k] = row;
  }
}

// ---------------- grouped expert GEMM: fp32-direct B, BM=256 ----------------
// Best-known core (R17/R21): A (bf16 K-major) via glds16 + T2 pre-swizzle
// (fc1 gathers indirectly via rows_token from token-indexed xg); B (fp32
// [k][n]) reg-staged transpose into padded Bs[n][68], depth-1 prefetch under
// MFMA.  BM=256, BN=64, BK=64; 256 thr = 4 waves, wave tile 64x64.
// fc2: split-K=2 via gridDim.z, bf16 partials summed in combine.
template<bool FC1>
__global__ __launch_bounds__(256, 2) void expert_gemm_k(
    const unsigned short* __restrict__ Ag,     // bf16: FC1 xg[tok][KD], else hbuf[row][KD]
    const float* __restrict__ Wg,              // fp32 [e][KD][ND]
    const float* __restrict__ bg,
    const int* __restrict__ cnt, const int* __restrict__ basev,
    const int* __restrict__ tile_e, const int* __restrict__ tile_m0,
    const int* __restrict__ ntt, const float* __restrict__ rows_w,
    const int* __restrict__ rows_token,
    unsigned short* __restrict__ hout, unsigned short* __restrict__ obuf)
{
  constexpr int KD = FC1 ? DIM : HID;
  constexpr int ND = FC1 ? HID : DIM;
  constexpr int KSPL = FC1 ? 1 : 2;
  constexpr int KLOC = KD / KSPL;
  constexpr int BM = 256, BN = 64, BK = 64, LDPB = 68;
  constexpr int NPH = KLOC / BK;               // 16 phases both layers
  if ((int)blockIdx.y >= ntt[0]) return;
  const int e  = tile_e[blockIdx.y], m0 = tile_m0[blockIdx.y];
  const int Ne = cnt[e], base = basev[e];
  const int nt = blockIdx.x, kz = blockIdx.z;
  const int kbase = kz * KLOC;
  __shared__ unsigned short As[BM][BK];        // 32 KB, linear (glds dest)
  __shared__ unsigned short Bs[BN][LDPB];      // 8.5 KB, transposed [n][k]
  const int tid = threadIdx.x, lane = tid & 63, wid = tid >> 6;

  // A staging: lane -> row lrow = lane>>3, src chunk = (lane&7)^(lrow&7) (T2)
  const int lrow = lane >> 3;
  const int lchunk = ((lane & 7) ^ (lrow & 7)) * 8;
  const unsigned short* asrc[8];
  unsigned short* aldst[8];
#pragma unroll
  for (int j = 0; j < 8; j++) {
    const int r = j * 32 + wid * 8 + lrow;
    int g = m0 + r; if (g >= Ne) g = Ne - 1;
    if constexpr (FC1) {
      const int tok = rows_token[base + g];    // indirect gather from xg
      asrc[j] = Ag + (size_t)tok * KD + kbase + lchunk;
    } else {
      asrc[j] = Ag + (size_t)(base + g) * KD + kbase + lchunk;
    }
    aldst[j] = &As[j * 32 + wid * 8][0];       // wave-uniform base
  }
  // B staging: thread t covers n4 = (t&15)*4, k-rows kr = (t>>4) + 16j, j=0..3
  const int bn4 = (tid & 15) * 4, bkr = tid >> 4;
  const float* bsrc = Wg + (size_t)e * KD * ND + (size_t)(kbase + bkr) * ND
                      + nt * BN + bn4;

  const int lr = lane & 15, lg = lane >> 4;
  const bool wactive = (m0 + wid * 64) < Ne;   // 4 waves stacked in m

  // A fragment pointers with matching XOR: chunk = (lg+4h) ^ (lr&7)
  const unsigned short* afp[4][2];
#pragma unroll
  for (int m = 0; m < 4; m++)
#pragma unroll
    for (int h = 0; h < 2; h++)
      afp[m][h] = &As[wid * 64 + m * 16 + lr][(((lg + 4*h) ^ (lr & 7)) * 8)];

  f32x4 acc[4][4];
#pragma unroll
  for (int m = 0; m < 4; m++)
#pragma unroll
    for (int n = 0; n < 4; n++) acc[m][n] = (f32x4){0.f, 0.f, 0.f, 0.f};

  float4 bst[4];
#define LOADB(K0)                                                            \
  { _Pragma("unroll")                                                        \
    for (int j = 0; j < 4; j++)                                              \
      bst[j] = *reinterpret_cast<const float4*>(bsrc + (size_t)((K0) + 16 * j) * ND); }

  // prologue: B fp32 for phase 0
  LOADB(0)

  for (int ph = 0; ph < NPH; ++ph) {
    const int k0 = ph * BK;
    __syncthreads();                           // prior phase's readers done
#pragma unroll
    for (int j = 0; j < 8; j++) glds16(asrc[j] + k0, aldst[j]);
    // write staged B (transpose into Bs[n][k])
#pragma unroll
    for (int j = 0; j < 4; j++) {
      Bs[bn4 + 0][bkr + 16 * j] = f2bf(bst[j].x);
      Bs[bn4 + 1][bkr + 16 * j] = f2bf(bst[j].y);
      Bs[bn4 + 2][bkr + 16 * j] = f2bf(bst[j].z);
      Bs[bn4 + 3][bkr + 16 * j] = f2bf(bst[j].w);
    }
    __syncthreads();                           // drain (glds + ds_write)
    if (ph + 1 < NPH) LOADB((ph + 1) * BK)     // prefetch next B under MFMA
    if (wactive) {
      __builtin_amdgcn_s_setprio(1);
#pragma unroll
      for (int h = 0; h < 2; h++) {
        short8 af[4], bb[4];
#pragma unroll
        for (int m = 0; m < 4; m++)
          af[m] = *reinterpret_cast<const short8*>(afp[m][h]);
#pragma unroll
        for (int n = 0; n < 4; n++)
          bb[n] = *reinterpret_cast<const short8*>(&Bs[n * 16 + lr][(lg + 4*h) * 8]);
#pragma unroll
        for (int m = 0; m < 4; m++)
#pragma unroll
          for (int n = 0; n < 4; n++)
            acc[m][n] = __builtin_amdgcn_mfma_f32_16x16x32_bf16(af[m], bb[n],
                                                                acc[m][n], 0, 0, 0);
      }
      __builtin_amdgcn_s_setprio(0);
    }
  }
#undef LOADB

  if (!wactive) return;
  // epilogue: C/D layout col = lane&15, row = (lane>>4)*4 + reg (m89-verified)
#pragma unroll
  for (int n = 0; n < 4; n++) {
    const int col = nt * BN + n * 16 + lr;
    const float bias = (kz == 0) ? bg[(size_t)e * ND + col] : 0.f;
#pragma unroll
    for (int m = 0; m < 4; m++) {
      const int rbase = m0 + wid * 64 + m * 16 + lg * 4;
#pragma unroll
      for (int v = 0; v < 4; v++) {
        const int r = rbase + v;
        if (r < Ne) {
          float val = acc[m][n][v] + bias;
          if constexpr (FC1) {
            val = 0.5f * val * (1.0f + erff(val * 0.70710678118654752440f));  // exact GELU
            hout[(size_t)(base + r) * HID + col] = f2bf(val);
          } else {
            obuf[(size_t)kz * (2 * T_TOK) * DIM + (size_t)(base + r) * DIM + col]
                = f2bf(val * rows_w[base + r]);          // bf16 partial
          }
        }
      }
    }
  }
}

// ---------------- combine: y = x + sum of 2 bf16 split-K partials per slot --
__global__ __launch_bounds__(256) void combine_k(const float* __restrict__ x,
    const unsigned short* __restrict__ obuf, const int* __restrict__ slot_of,
    float* __restrict__ out)
{
  const int t = blockIdx.x, c = threadIdx.x;
  const int s0 = slot_of[2*t], s1 = slot_of[2*t+1];
  const size_t PSZ = (size_t)(2 * T_TOK) * DIM;
  const float4 a = reinterpret_cast<const float4*>(x + (size_t)t * DIM)[c];
  float r0 = a.x, r1 = a.y, r2 = a.z, r3 = a.w;
#pragma unroll
  for (int kz = 0; kz < 2; kz++) {
    ushort4 p = *reinterpret_cast<const ushort4*>(
        obuf + kz * PSZ + (size_t)s0 * DIM + c * 4);
    r0 += bf2f(p.x); r1 += bf2f(p.y); r2 += bf2f(p.z); r3 += bf2f(p.w);
    ushort4 q = *reinterpret_cast<const ushort4*>(
        obuf + kz * PSZ + (size_t)s1 * DIM + c * 4);
    r0 += bf2f(q.x); r1 += bf2f(q.y); r2 += bf2f(q.z); r3 += bf2f(q.w);
  }
  float4 r; r.x = r0; r.y = r1; r.z = r2; r.w = r3;
  reinterpret_cast<float4*>(out + (size_t)t * DIM)[c] = r;
}

extern "C" void kernel_launch(void* const* d_in, const int* in_sizes, int n_in,
                              void* d_out, int out_size, void* d_ws, size_t ws_size,
                              hipStream_t stream) {
  const float* x  = (const float*)d_in[0];
  const float* Wr = (const float*)d_in[1];
  const float* br = (const float*)d_in[2];
  const float* W1 = (const float*)d_in[3];
  const float* b1 = (const float*)d_in[4];
  const float* W2 = (const float*)d_in[5];
  const float* b2 = (const float*)d_in[6];
  float* out = (float*)d_out;
  char* ws = (char*)d_ws;

  int*   cnt        = (int*)  (ws + 0);
  int*   fill       = (int*)  (ws + 64);
  int*   basev      = (int*)  (ws + 128);
  int*   ntt        = (int*)  (ws + 192);
  int*   tile_e     = (int*)  (ws + 1024);
  int*   tile_m0    = (int*)  (ws + 2048);
  int*   re         = (int*)  (ws + 16384);
  float* rwv        = (float*)(ws + 32768);
  int*   rows_token = (int*)  (ws + 49152);
  float* rows_w     = (float*)(ws + 65536);
  int*   slot_of    = (int*)  (ws + 81920);
  unsigned short* xg   = (unsigned short*)(ws + ((size_t)(1 << 17)));                       // 4 MB (token-indexed)
  unsigned short* hbuf = (unsigned short*)(ws + ((size_t)(1 << 17) + ((size_t)8  << 20)));  // 16 MB
  unsigned short* obuf = (unsigned short*)(ws + ((size_t)(1 << 17) + ((size_t)24 << 20)));  // 2x8 MB bf16 partials

  hipMemsetAsync(ws, 0, 256, stream);          // cnt / fill / basev / ntt
  router_k<<<dim3(T_TOK / 32), dim3(256), 0, stream>>>(x, Wr, br, re, rwv, cnt, xg);
  scan_k<<<dim3(1), dim3(64), 0, stream>>>(cnt, basev, tile_e, tile_m0, ntt);
  scatter_k<<<dim3(T_TOK / 256), dim3(256), 0, stream>>>(re, rwv, basev, fill,
                                                         rows_token, rows_w, slot_of);
  expert_gemm_k<true><<<dim3(HID / 64, MAXMT, 1), dim3(256), 0, stream>>>(
      xg, W1, b1, cnt, basev, tile_e, tile_m0, ntt, rows_w, rows_token, hbuf, obuf);
  expert_gemm_k<false><<<dim3(DIM / 64, MAXMT, 2), dim3(256), 0, stream>>>(
      hbuf, W2, b2, cnt, basev, tile_e, tile_m0, ntt, rows_w, rows_token, hbuf, obuf);
  combine_k<<<dim3(T_TOK), dim3(256), 0, stream>>>(x, obuf, slot_of, out);
}